// Round 9
// baseline (48.100 us; speedup 1.0000x reference)
//
#include <hip/hip_runtime.h>

// Problem constants (from reference setup_inputs)
#define BB 32     // batch
#define UU 1152   // input_units
#define NN 10     // num_units
#define CC 8      // input_channels
#define DD 16     // channels_per_unit
#define EPS 1e-8f
#define INV_LN2 1.44269504088896341f

// inputs : (B, C, U)        float32
// weights: (U, N, C, D)     float32
// out    : (B, N, U, C, D)  float32
//
// R9: break the per-n-step serial chain + get under the 64-VGPR cliff.
//  - W2[u,n,c] = sum_d w^2 precomputed by a tiny kernel into d_ws (368 KB,
//    L2-resident). Then sq0 = v^2 * W2 / 256: the kk->exp2 chain starts
//    right after two scalar loads, overlapping the q computation, and the
//    iter-0 DPP reduction disappears (~12 VALU + 2 DPP saved per n-step).
//  - no prefetch pipeline (was neutral, cost 16 VGPR); __launch_bounds__(256,8)
//    pins <=64 VGPR -> 8 waves/SIMD for latency hiding.
//  - kept from R8: 8-wide lane split (2 lanes/group), b-swizzled blocks
//    (weights L2-resident), plain f32x4 stores, base-2 logits, folded squash
//    k_o = A * rsqrt(A + eps*S^2) * rcp(S^2 + A).

typedef float f32x4 __attribute__((ext_vector_type(4)));

__device__ __forceinline__ float rcp_fast(float x) { return __builtin_amdgcn_rcpf(x); }
__device__ __forceinline__ float rsq_fast(float x) { return __builtin_amdgcn_rsqf(x); }

#if __has_builtin(__builtin_amdgcn_exp2f)
__device__ __forceinline__ float exp2_fast(float x) { return __builtin_amdgcn_exp2f(x); }
#else
__device__ __forceinline__ float exp2_fast(float x) { return __expf(x * 0.6931471805599453f); }
#endif

// sum across a lane PAIR (lanes 2k, 2k+1): one DPP xor-1 step
__device__ __forceinline__ float pair_sum(float x) {
    float y = __int_as_float(
        __builtin_amdgcn_update_dpp(0, __float_as_int(x), 0xB1, 0xF, 0xF, true)); // [1,0,3,2]
    return x + y;
}

__device__ __forceinline__ float hsum4(f32x4 a) {
    return (a.x + a.y) + (a.z + a.w);
}

__device__ __forceinline__ f32x4 exp2_v4(f32x4 a) {
    f32x4 r;
    r.x = exp2_fast(a.x); r.y = exp2_fast(a.y);
    r.z = exp2_fast(a.z); r.w = exp2_fast(a.w);
    return r;
}

// ---- kernel 1: W2[u,n,c] = sum_d weights[u,n,c,d]^2  (92160 entries) ----
__global__ __launch_bounds__(256) void w2_kernel(
    const float* __restrict__ weights, float* __restrict__ w2)
{
    int idx = blockIdx.x * blockDim.x + threadIdx.x;   // 0 .. 92159
    const float* wp = weights + (long long)idx * DD;
    f32x4 a = *reinterpret_cast<const f32x4*>(wp);
    f32x4 b = *reinterpret_cast<const f32x4*>(wp + 4);
    f32x4 c = *reinterpret_cast<const f32x4*>(wp + 8);
    f32x4 d = *reinterpret_cast<const f32x4*>(wp + 12);
    f32x4 s = a * a + b * b + c * c + d * d;
    w2[idx] = hsum4(s);
}

// ---- kernel 2: routing ----
template <bool USE_W2>
__global__ __launch_bounds__(256, 8) void caps_route_kernel(
    const float* __restrict__ inputs,
    const float* __restrict__ weights,
    const float* __restrict__ w2tab,
    float* __restrict__ out)
{
    int tid = threadIdx.x;
    int bi  = blockIdx.x;         // 2304 blocks = 32 b * 72 ublocks
    int b   = bi & 31;            // consecutive blocks share a u-slice of weights
    int ub  = bi >> 5;

    int sub    = tid & 1;         // low/high 8 elements of D
    int c      = (tid >> 1) & 7;
    int ulocal = tid >> 4;        // 0..15
    int u      = ub * 16 + ulocal;

    float v  = inputs[(b * CC + c) * UU + u];
    float v2 = v * v * (1.0f / 256.0f);

    int wslice = (u * NN + 0) * CC + c;                 // [u][n][c] index, n=0
    const float* wbase = weights + wslice * DD + sub * 8;
    const float* w2p   = w2tab + wslice;
    float*       obase = out + ((b * NN * UU + u) * CC + c) * DD + sub * 8;
    const int WSTRIDE = CC * DD;        // 128 floats between n-slices of weights
    const int OSTRIDE = UU * CC * DD;   // floats between n-slices of out

    #pragma unroll 1
    for (int n = 0; n < NN; ++n) {
        f32x4 wa = *reinterpret_cast<const f32x4*>(wbase + n * WSTRIDE);
        f32x4 wb = *reinterpret_cast<const f32x4*>(wbase + n * WSTRIDE + 4);

        f32x4 pa = wa * v, pb = wb * v;
        f32x4 qa = pa * pa, qb = pb * pb;

        // ---- iter 0 (folded): sq0 = v^2 * sum(w^2) / 256 ----
        float sq0;
        if (USE_W2) {
            sq0 = v2 * w2p[n * CC];                     // scalar L2 load
        } else {
            sq0 = pair_sum(hsum4(qa + qb)) * (1.0f / 256.0f);
        }
        float kk = sq0 * rcp_fast(1.0f + sq0) * rsq_fast(sq0 + EPS)
                   * (INV_LN2 / 16.0f);
        f32x4 La = kk * qa, Lb = kk * qb;

        // ---- iter 1 (base-2 logit update via m = e*q) ----
        {
            f32x4 ea = exp2_v4(La), eb = exp2_v4(Lb);
            float S = pair_sum(hsum4(ea + eb));
            f32x4 ma = ea * qa, mb = eb * qb;
            float A = pair_sum(hsum4(ma * ea + mb * eb));
            float Ssq = S * S;
            float k = A * rsq_fast(fmaf(EPS, Ssq, A)) * rcp_fast(Ssq + A)
                      * INV_LN2;
            La += k * ma;  Lb += k * mb;
        }

        // ---- iter 2 (final; logit update dead) ----
        {
            f32x4 ea = exp2_v4(La), eb = exp2_v4(Lb);
            float S = pair_sum(hsum4(ea + eb));
            f32x4 ta = ea * pa, tb = eb * pb;
            float A = pair_sum(hsum4(ta * ta + tb * tb));
            float Ssq = S * S;
            float ko = A * rsq_fast(fmaf(EPS, Ssq, A)) * rcp_fast(Ssq + A);
            *reinterpret_cast<f32x4*>(obase + n * OSTRIDE)     = ko * ta;
            *reinterpret_cast<f32x4*>(obase + n * OSTRIDE + 4) = ko * tb;
        }
    }
}

extern "C" void kernel_launch(void* const* d_in, const int* in_sizes, int n_in,
                              void* d_out, int out_size, void* d_ws, size_t ws_size,
                              hipStream_t stream) {
    const float* inputs  = (const float*)d_in[0];
    const float* weights = (const float*)d_in[1];
    float* out = (float*)d_out;

    const int W2N = UU * NN * CC;                     // 92,160
    const bool use_w2 = (ws_size >= (size_t)W2N * sizeof(float));

    const long long total = (long long)BB * UU * CC * 2;  // 589,824 = 2304*256
    const int block = 256;
    const int grid = (int)(total / block);                // 2304

    if (use_w2) {
        float* w2 = (float*)d_ws;
        w2_kernel<<<W2N / 256, 256, 0, stream>>>(weights, w2);
        caps_route_kernel<true><<<grid, block, 0, stream>>>(inputs, weights, w2, out);
    } else {
        caps_route_kernel<false><<<grid, block, 0, stream>>>(inputs, weights, nullptr, out);
    }
}

// Round 10
// 42.851 us; speedup vs baseline: 1.1225x; 1.1225x over previous
//
#include <hip/hip_runtime.h>

// Problem constants (from reference setup_inputs)
#define BB 32     // batch
#define UU 1152   // input_units
#define NN 10     // num_units
#define CC 8      // input_channels
#define DD 16     // channels_per_unit
#define EPS 1e-8f
#define INV_LN2 1.44269504088896341f

// inputs : (B, C, U)        float32
// weights: (U, N, C, D)     float32
// out    : (B, N, U, C, D)  float32
//
// R10: one (b,n,u,c,sub) slice per thread -- n moved OUT of the thread into
// the grid, with block order (b,n) outer / u-chunk INNER:
//   blockIdx = (b*NN + n)*72 + uc
// so the ~2048 resident blocks form ~28 LINEAR write streams (adjacent
// blocks write adjacent 8 KB chunks of the same (b,n) u-range) instead of
// ~20k scattered 8 KB windows -> fill-like DRAM row locality on the 189 MB
// output stream. Per-thread state drops to ~30 VGPR -> 8 waves/SIMD.
// Math identical to R8 (folded iter0, base-2 logits, folded squash
// k_o = A * rsqrt(A + eps*S^2) * rcp(S^2 + A), 8-wide lane split, one
// DPP xor-1 step per 16-element reduction).

typedef float f32x4 __attribute__((ext_vector_type(4)));

__device__ __forceinline__ float rcp_fast(float x) { return __builtin_amdgcn_rcpf(x); }
__device__ __forceinline__ float rsq_fast(float x) { return __builtin_amdgcn_rsqf(x); }

#if __has_builtin(__builtin_amdgcn_exp2f)
__device__ __forceinline__ float exp2_fast(float x) { return __builtin_amdgcn_exp2f(x); }
#else
__device__ __forceinline__ float exp2_fast(float x) { return __expf(x * 0.6931471805599453f); }
#endif

// sum across a lane PAIR (lanes 2k, 2k+1): one DPP xor-1 step
__device__ __forceinline__ float pair_sum(float x) {
    float y = __int_as_float(
        __builtin_amdgcn_update_dpp(0, __float_as_int(x), 0xB1, 0xF, 0xF, true)); // [1,0,3,2]
    return x + y;
}

__device__ __forceinline__ float hsum4(f32x4 a) {
    return (a.x + a.y) + (a.z + a.w);
}

__device__ __forceinline__ f32x4 exp2_v4(f32x4 a) {
    f32x4 r;
    r.x = exp2_fast(a.x); r.y = exp2_fast(a.y);
    r.z = exp2_fast(a.z); r.w = exp2_fast(a.w);
    return r;
}

__global__ __launch_bounds__(256) void caps_route_kernel(
    const float* __restrict__ inputs,
    const float* __restrict__ weights,
    float* __restrict__ out)
{
    int tid = threadIdx.x;
    int bi  = blockIdx.x;           // 23,040 blocks = (32 b * 10 n) * 72 uc
    int uc  = bi % 72;              // u-chunk FASTEST -> clustered write front
    int bn  = bi / 72;
    int n   = bn % NN;
    int b   = bn / NN;

    int sub = tid & 1;              // low/high 8 elements of D
    int c   = (tid >> 1) & 7;
    int u   = uc * 16 + (tid >> 4); // 16 u per block

    float v = inputs[(b * CC + c) * UU + u];

    const float* wp = weights + ((u * NN + n) * CC + c) * DD + sub * 8;
    f32x4 wa = *reinterpret_cast<const f32x4*>(wp);
    f32x4 wb = *reinterpret_cast<const f32x4*>(wp + 4);

    f32x4 pa = wa * v, pb = wb * v;
    f32x4 qa = pa * pa, qb = pb * pb;

    // ---- iter 0 (folded): softmax uniform; L = scale0*INV_LN2/16 * q ----
    float sq0 = pair_sum(hsum4(qa + qb)) * (1.0f / 256.0f);
    float kk = sq0 * rcp_fast(1.0f + sq0) * rsq_fast(sq0 + EPS)
               * (INV_LN2 / 16.0f);
    f32x4 La = kk * qa, Lb = kk * qb;

    // ---- iter 1 (base-2 logit update via m = e*q) ----
    {
        f32x4 ea = exp2_v4(La), eb = exp2_v4(Lb);
        float S = pair_sum(hsum4(ea + eb));
        f32x4 ma = ea * qa, mb = eb * qb;
        float A = pair_sum(hsum4(ma * ea + mb * eb));
        float Ssq = S * S;
        float k = A * rsq_fast(fmaf(EPS, Ssq, A)) * rcp_fast(Ssq + A)
                  * INV_LN2;
        La += k * ma;  Lb += k * mb;
    }

    // ---- iter 2 (final; logit update dead) ----
    {
        f32x4 ea = exp2_v4(La), eb = exp2_v4(Lb);
        float S = pair_sum(hsum4(ea + eb));
        f32x4 ta = ea * pa, tb = eb * pb;
        float A = pair_sum(hsum4(ta * ta + tb * tb));
        float Ssq = S * S;
        float ko = A * rsq_fast(fmaf(EPS, Ssq, A)) * rcp_fast(Ssq + A);

        float* op = out + ((b * NN + n) * UU + u) * (CC * DD) + c * DD + sub * 8;
        *reinterpret_cast<f32x4*>(op)     = ko * ta;
        *reinterpret_cast<f32x4*>(op + 4) = ko * tb;
    }
}

extern "C" void kernel_launch(void* const* d_in, const int* in_sizes, int n_in,
                              void* d_out, int out_size, void* d_ws, size_t ws_size,
                              hipStream_t stream) {
    const float* inputs  = (const float*)d_in[0];
    const float* weights = (const float*)d_in[1];
    float* out = (float*)d_out;

    const long long total = (long long)BB * NN * UU * CC * 2;  // 5,898,240 = 23040*256
    const int block = 256;
    const int grid = (int)(total / block);                     // 23,040
    caps_route_kernel<<<grid, block, 0, stream>>>(inputs, weights, out);
}